// Round 1
// 1562.140 us; speedup vs baseline: 1.1176x; 1.1176x over previous
//
#include <hip/hip_runtime.h>
#include <hip/hip_bf16.h>

#define NN 98
#define CC 192
#define NH 6
#define HDIM 32
#define NWIN 64
#define MPAD 100
#define NSTR 200   // xs / O_lds row stride (bf16 elems): 400B, 16B-aligned rows
#define SWS 1920   // per-wave staging elems (3840B)

// packed weight fragment array sizes (bf16 elems)
#define WKV_ELEMS 73728   // NH * 6ks * 4frag * 512
#define WQ_ELEMS  36864   // NH * 6ks * 2frag * 512
#define WP_ELEMS  36864

typedef float f32x4 __attribute__((ext_vector_type(4)));
typedef __bf16 bf16x8 __attribute__((ext_vector_type(8)));
typedef __bf16 bf16x4 __attribute__((ext_vector_type(4)));

__device__ __forceinline__ f32x4 mfma_bf16(bf16x8 a, bf16x8 b, f32x4 c) {
  return __builtin_amdgcn_mfma_f32_16x16x32_bf16(a, b, c, 0, 0, 0);
}

__device__ __forceinline__ bf16x8 zero8() {
  bf16x8 z;
#pragma unroll
  for (int i = 0; i < 8; ++i) z[i] = (__bf16)0.0f;
  return z;
}

__device__ __forceinline__ float fast_exp2(float x) {
#if __has_builtin(__builtin_amdgcn_exp2f)
  return __builtin_amdgcn_exp2f(x);
#else
  return exp2f(x);
#endif
}

// A-fragment from a [98][NSTR] LDS tile; rows >= 98 -> zero
__device__ __forceinline__ bf16x8 ldlds8(const __bf16* p, int row, int k0) {
  int rc = row < NN ? row : (NN - 1);
  bf16x8 v = *(const bf16x8*)(p + rc * NSTR + k0);
  if (row >= NN) v = zero8();
  return v;
}

// Pre-pad bias (gathered from rpb table) and mask to inner stride 100 with -1e30,
// pre-scaled by log2(e) so softmax uses raw exp2. Also pack qkv_w / proj_w into
// bf16 MFMA-fragment order: [head][ks][frag][lane][8], one coalesced 16B/lane load.
__global__ void prep_kernel(const float* __restrict__ mask,
                            const float* __restrict__ rpb,
                            const int* __restrict__ rel_idx,
                            const float* __restrict__ qkv_w,
                            const float* __restrict__ proj_w,
                            float* __restrict__ biasp,
                            float* __restrict__ maskp,
                            __bf16* __restrict__ wkvp,
                            __bf16* __restrict__ wqp,
                            __bf16* __restrict__ wpp) {
  const float LOG2E = 1.4426950408889634f;
  int i = blockIdx.x * 256 + threadIdx.x;
  if (i < NH * NN * MPAD) {
    int m = i % MPAD;
    int rem = i / MPAD;
    int n = rem % NN;
    int h = rem / NN;
    biasp[i] = (m < NN) ? rpb[rel_idx[n * NN + m] * NH + h] * LOG2E : -1e30f;
  }
  if (i < NWIN * NN * MPAD) {
    int m = i % MPAD;
    int rem = i / MPAD;
    int n = rem % NN;
    int wi = rem / NN;
    maskp[i] = (m < NN) ? mask[(wi * NN + n) * NN + m] * LOG2E : -1e30f;
  }
  if (i < WKV_ELEMS) {
    // ((w*6+ks)*4+f)*512 + lane*8 + j ; f0,f1 = K cols 0/16 ; f2,f3 = V cols 0/16
    int j = i & 7;
    int lane = (i >> 3) & 63;
    int f = (i >> 9) & 3;
    int t = i >> 11;  // w*6 + ks
    int ks = t % 6;
    int w = t / 6;
    int l15 = lane & 15, quad = lane >> 4;
    int row = (f < 2 ? CC : 2 * CC) + w * HDIM + (f & 1) * 16 + l15;
    int col = ks * 32 + quad * 8 + j;
    wkvp[i] = (__bf16)qkv_w[row * CC + col];
  }
  if (i < WQ_ELEMS) {
    // ((w*6+ks)*2+f)*512 + lane*8 + j
    int j = i & 7;
    int lane = (i >> 3) & 63;
    int f = (i >> 9) & 1;
    int t = i >> 10;  // w*6 + ks
    int ks = t % 6;
    int w = t / 6;
    int l15 = lane & 15, quad = lane >> 4;
    int row = w * HDIM + f * 16 + l15;
    int col = ks * 32 + quad * 8 + j;
    wqp[i] = (__bf16)qkv_w[row * CC + col];
    wpp[i] = (__bf16)proj_w[row * CC + col];
  }
}

// Register-pressure note: K/V/Q projections run as SEPARATE passes so only
// acc[2][7] (56 f32) of accumulators is live at once (was accA[4][7]=112 ->
// combined VGPR+AGPR ~256/wave -> 2 waves/SIMD -> single block/CU resident).
__global__ __launch_bounds__(384, 3) void attn_kernel(
    const float* __restrict__ x,
    const float* __restrict__ qkv_b,
    const float* __restrict__ proj_b,
    const float* __restrict__ biasp,
    const float* __restrict__ maskp,
    const __bf16* __restrict__ wkvp,
    const __bf16* __restrict__ wqp,
    const __bf16* __restrict__ wpp,
    float* __restrict__ out) {
  __shared__ alignas(16) __bf16 xs[NN * NSTR];      // 39200 B; reused as O_lds
  __shared__ alignas(16) __bf16 stage[NH * SWS];    // 23040 B; per-wave private staging

  const int b = blockIdx.x;
  const int tid = threadIdx.x;
  const int w = tid >> 6;     // wave index == head index
  const int lane = tid & 63;
  const int l15 = lane & 15;
  const int quad = lane >> 4;
  __bf16* st = stage + w * SWS;

  // ---- stage x_b into LDS as bf16 ----
  const float* xb = x + (size_t)b * (NN * CC);
  for (int i = tid; i < NN * CC / 4; i += 384) {
    int e = i * 4;
    int n = e / CC;
    int c = e - n * CC;
    f32x4 v = *(const f32x4*)(xb + e);
    bf16x4 p;
    p[0] = (__bf16)v[0]; p[1] = (__bf16)v[1]; p[2] = (__bf16)v[2]; p[3] = (__bf16)v[3];
    *(bf16x4*)&xs[n * NSTR + c] = p;
  }
  __syncthreads();

  f32x4 acc[2][7];

  // ==== K pass ====
#pragma unroll
  for (int ct = 0; ct < 2; ++ct) {
    float bb = qkv_b[CC + w * HDIM + ct * 16 + l15];
#pragma unroll
    for (int rt = 0; rt < 7; ++rt) { f32x4 t = {bb, bb, bb, bb}; acc[ct][rt] = t; }
  }
  {
    const __bf16* wb = wkvp + (size_t)(w * 24) * 512 + lane * 8;
#pragma unroll
    for (int ks = 0; ks < 6; ++ks) {
      bf16x8 b0 = *(const bf16x8*)(wb + (ks * 4 + 0) * 512);
      bf16x8 b1 = *(const bf16x8*)(wb + (ks * 4 + 1) * 512);
      const int k0 = ks * 32 + quad * 8;
#pragma unroll
      for (int rt = 0; rt < 7; ++rt) {
        bf16x8 a = ldlds8(xs, rt * 16 + l15, k0);
        acc[0][rt] = mfma_bf16(a, b0, acc[0][rt]);
        acc[1][rt] = mfma_bf16(a, b1, acc[1][rt]);
      }
    }
  }

  // stage K tile-by-tile (wave-private [16][40]) -> A-frags ka[mt]
  bf16x8 ka[7];
#pragma unroll
  for (int rt = 0; rt < 7; ++rt) {
#pragma unroll
    for (int ct = 0; ct < 2; ++ct) {
      f32x4 v = acc[ct][rt];
      int hd = ct * 16 + l15;
#pragma unroll
      for (int r = 0; r < 4; ++r) st[(quad * 4 + r) * 40 + hd] = (__bf16)v[r];
    }
    bf16x8 f = *(const bf16x8*)&st[l15 * 40 + quad * 8];
    if (rt * 16 + l15 >= NN) f = zero8();
    ka[rt] = f;
  }

  // ==== V pass ====
#pragma unroll
  for (int ct = 0; ct < 2; ++ct) {
    float bb = qkv_b[2 * CC + w * HDIM + ct * 16 + l15];
#pragma unroll
    for (int rt = 0; rt < 7; ++rt) { f32x4 t = {bb, bb, bb, bb}; acc[ct][rt] = t; }
  }
  {
    const __bf16* wb = wkvp + (size_t)(w * 24) * 512 + lane * 8;
#pragma unroll
    for (int ks = 0; ks < 6; ++ks) {
      bf16x8 b0 = *(const bf16x8*)(wb + (ks * 4 + 2) * 512);
      bf16x8 b1 = *(const bf16x8*)(wb + (ks * 4 + 3) * 512);
      const int k0 = ks * 32 + quad * 8;
#pragma unroll
      for (int rt = 0; rt < 7; ++rt) {
        bf16x8 a = ldlds8(xs, rt * 16 + l15, k0);
        acc[0][rt] = mfma_bf16(a, b0, acc[0][rt]);
        acc[1][rt] = mfma_bf16(a, b1, acc[1][rt]);
      }
    }
  }

  // stage V in row-tile pairs (wave-private [32][40]) -> A-frags va[dt][ks]
  bf16x8 va[2][4];
#pragma unroll
  for (int ks = 0; ks < 4; ++ks) {
#pragma unroll
    for (int h2 = 0; h2 < 2; ++h2) {
      int rt = 2 * ks + h2;
      if (rt < 7) {
#pragma unroll
        for (int ct = 0; ct < 2; ++ct) {
          f32x4 v = acc[ct][rt];
          int d = ct * 16 + l15;
          int mloc = h2 * 16 + quad * 4;
          bf16x4 p;
#pragma unroll
          for (int r = 0; r < 4; ++r) p[r] = (__bf16)v[r];
          *(bf16x4*)&st[d * 40 + mloc] = p;
        }
      }
    }
#pragma unroll
    for (int dt = 0; dt < 2; ++dt) {
      bf16x8 f = *(const bf16x8*)&st[(dt * 16 + l15) * 40 + quad * 8];
      if (ks == 3 && quad >= 2) f = zero8();  // m >= 112 zeroed
      va[dt][ks] = f;
    }
  }

  // ==== Q pass ====
#pragma unroll
  for (int ct = 0; ct < 2; ++ct) {
    float bq = qkv_b[w * HDIM + ct * 16 + l15];
#pragma unroll
    for (int rt = 0; rt < 7; ++rt) { f32x4 t = {bq, bq, bq, bq}; acc[ct][rt] = t; }
  }
  {
    const __bf16* wb = wqp + (size_t)(w * 12) * 512 + lane * 8;
#pragma unroll
    for (int ks = 0; ks < 6; ++ks) {
      bf16x8 b0 = *(const bf16x8*)(wb + (ks * 2 + 0) * 512);
      bf16x8 b1 = *(const bf16x8*)(wb + (ks * 2 + 1) * 512);
      const int k0 = ks * 32 + quad * 8;
#pragma unroll
      for (int rt = 0; rt < 7; ++rt) {
        bf16x8 a = ldlds8(xs, rt * 16 + l15, k0);
        acc[0][rt] = mfma_bf16(a, b0, acc[0][rt]);
        acc[1][rt] = mfma_bf16(a, b1, acc[1][rt]);
      }
    }
  }

  // stage Q (scale * log2e folded) tile-by-tile -> B-frags qb[nb]
  const float qscale = 0.17677669529663687f * 1.4426950408889634f;
  bf16x8 qb[7];
#pragma unroll
  for (int rt = 0; rt < 7; ++rt) {
#pragma unroll
    for (int ct = 0; ct < 2; ++ct) {
      f32x4 v = acc[ct][rt];
      int hd = ct * 16 + l15;
#pragma unroll
      for (int r = 0; r < 4; ++r) st[(quad * 4 + r) * 40 + hd] = (__bf16)(v[r] * qscale);
    }
    bf16x8 f = *(const bf16x8*)&st[l15 * 40 + quad * 8];
    if (rt * 16 + l15 >= NN) f = zero8();
    qb[rt] = f;
  }

  __syncthreads();  // all waves done reading xs; it becomes O_lds
  __bf16* O_lds = xs;

  // ---- attention: S^T = K Q^T per 16-column block; lane-local softmax; O^T = V^T P^T ----
  const int wmask = b & (NWIN - 1);
#pragma unroll 1
  for (int nb = 0; nb < 7; ++nb) {
    const f32x4 z4 = {0.f, 0.f, 0.f, 0.f};
    f32x4 sacc[7];
#pragma unroll
    for (int mt = 0; mt < 7; ++mt) sacc[mt] = mfma_bf16(ka[mt], qb[nb], z4);

    int n = nb * 16 + l15;
    bool nvalid = (n < NN);
    int nc = nvalid ? n : 0;
    const float* bp = biasp + (size_t)(w * NN + nc) * MPAD;
    const float* mp = maskp + (size_t)(wmask * NN + nc) * MPAD;

    float mx = -3.0e38f;
#pragma unroll
    for (int mt = 0; mt < 7; ++mt) {
      int m0 = mt * 16 + quad * 4;
      bool ld = nvalid && (m0 < MPAD);
      f32x4 add = z4;
      if (ld) {
        f32x4 bm = *(const f32x4*)(bp + m0);
        f32x4 mm = *(const f32x4*)(mp + m0);
        add = bm + mm;  // padded entries are -1e30, already log2e-scaled
      }
#pragma unroll
      for (int r = 0; r < 4; ++r) {
        float v = ld ? (sacc[mt][r] + add[r]) : -1e30f;
        sacc[mt][r] = v;
        mx = fmaxf(mx, v);
      }
    }
    mx = fmaxf(mx, __shfl_xor(mx, 16, 64));
    mx = fmaxf(mx, __shfl_xor(mx, 32, 64));
    float sum = 0.f;
#pragma unroll
    for (int mt = 0; mt < 7; ++mt) {
#pragma unroll
      for (int r = 0; r < 4; ++r) {
        float p = fast_exp2(sacc[mt][r] - mx);
        sacc[mt][r] = p;
        sum += p;
      }
    }
    sum += __shfl_xor(sum, 16, 64);
    sum += __shfl_xor(sum, 32, 64);
    float rinv = 1.0f / sum;

    // write P^T to wave-private [16][120] LDS, reload as B-frags
#pragma unroll
    for (int mt = 0; mt < 7; ++mt) {
      bf16x4 p;
#pragma unroll
      for (int r = 0; r < 4; ++r) p[r] = (__bf16)sacc[mt][r];
      *(bf16x4*)&st[l15 * 120 + mt * 16 + quad * 4] = p;
    }
    bf16x8 pf[4];
#pragma unroll
    for (int ks = 0; ks < 4; ++ks) {
      bf16x8 f = *(const bf16x8*)&st[l15 * 120 + ks * 32 + quad * 8];
      if (ks == 3 && quad >= 2) f = zero8();
      pf[ks] = f;
    }

#pragma unroll
    for (int dt = 0; dt < 2; ++dt) {
      f32x4 o = z4;
#pragma unroll
      for (int ks = 0; ks < 4; ++ks) o = mfma_bf16(va[dt][ks], pf[ks], o);
      if (nvalid) {
        bf16x4 p;
#pragma unroll
        for (int r = 0; r < 4; ++r) p[r] = (__bf16)(o[r] * rinv);
        *(bf16x4*)&O_lds[n * NSTR + w * HDIM + dt * 16 + quad * 4] = p;
      }
    }
  }
  __syncthreads();  // O_lds complete

  // ---- output projection: out = O @ proj_w^T + proj_b ----
  f32x4 accP[2][7];
#pragma unroll
  for (int ct = 0; ct < 2; ++ct) {
    float pb = proj_b[w * HDIM + ct * 16 + l15];
#pragma unroll
    for (int rt = 0; rt < 7; ++rt) { f32x4 t = {pb, pb, pb, pb}; accP[ct][rt] = t; }
  }
  {
    const __bf16* wb = wpp + (size_t)(w * 12) * 512 + lane * 8;
#pragma unroll
    for (int ks = 0; ks < 6; ++ks) {
      bf16x8 b0 = *(const bf16x8*)(wb + (ks * 2 + 0) * 512);
      bf16x8 b1 = *(const bf16x8*)(wb + (ks * 2 + 1) * 512);
      const int k0 = ks * 32 + quad * 8;
#pragma unroll
      for (int rt = 0; rt < 7; ++rt) {
        bf16x8 a = ldlds8(O_lds, rt * 16 + l15, k0);
        accP[0][rt] = mfma_bf16(a, b0, accP[0][rt]);
        accP[1][rt] = mfma_bf16(a, b1, accP[1][rt]);
      }
    }
  }

  float* ob = out + (size_t)b * (NN * CC);
#pragma unroll
  for (int ct = 0; ct < 2; ++ct) {
    int cout = w * HDIM + ct * 16 + l15;
#pragma unroll
    for (int rt = 0; rt < 7; ++rt) {
      f32x4 v = accP[ct][rt];
#pragma unroll
      for (int r = 0; r < 4; ++r) {
        int n = rt * 16 + quad * 4 + r;
        if (n < NN) ob[n * CC + cout] = v[r];
      }
    }
  }
}

extern "C" void kernel_launch(void* const* d_in, const int* in_sizes, int n_in,
                              void* d_out, int out_size, void* d_ws, size_t ws_size,
                              hipStream_t stream) {
  const float* x = (const float*)d_in[0];
  const float* mask = (const float*)d_in[1];
  const float* qkv_w = (const float*)d_in[2];
  const float* qkv_b = (const float*)d_in[3];
  const float* proj_w = (const float*)d_in[4];
  const float* proj_b = (const float*)d_in[5];
  const float* rpb = (const float*)d_in[6];
  const int* rel_idx = (const int*)d_in[7];

  float* biasp = (float*)d_ws;                       // 6*98*100 floats
  float* maskp = biasp + NH * NN * MPAD;             // 64*98*100 floats
  __bf16* wkvp = (__bf16*)(maskp + NWIN * NN * MPAD);  // 73728 bf16 (16B-aligned)
  __bf16* wqp = wkvp + WKV_ELEMS;                      // 36864 bf16
  __bf16* wpp = wqp + WQ_ELEMS;                        // 36864 bf16

  int prep_threads = NWIN * NN * MPAD;               // 627200 (covers all pack jobs)
  prep_kernel<<<(prep_threads + 255) / 256, 256, 0, stream>>>(
      mask, rpb, rel_idx, qkv_w, proj_w, biasp, maskp, wkvp, wqp, wpp);
  attn_kernel<<<4096, 384, 0, stream>>>(x, qkv_b, proj_b, biasp, maskp,
                                        wkvp, wqp, wpp, (float*)d_out);
}